// Round 2
// baseline (22142.891 us; speedup 1.0000x reference)
//
#include <hip/hip_runtime.h>
#include <math.h>

#define Bsz 64
#define Tsz 1024
#define Esz 300
#define Hsz 200
#define Gsz 800   // 4*H
#define NTOK (Bsz*Tsz)

// ---------------- lengths: lens[b] = sum(mask[b,:]) ----------------
// mask may arrive as 1-byte bools or 4-byte ints. Sniff: len >= 512 always,
// so if 1-byte layout, byte[1]==1; if int32 (value 0/1), byte[1]==0.
__global__ __launch_bounds__(256) void k_lengths(const void* __restrict__ mraw,
                                                 int* __restrict__ lens) {
  __shared__ int red[256];
  const unsigned char* mb = (const unsigned char*)mraw;
  const int isbool = (mb[1] != 0);
  int b = blockIdx.x, tid = threadIdx.x;
  int s = 0;
  if (isbool) {
    const unsigned char* row = mb + (size_t)b * Tsz;
    for (int i = tid; i < Tsz; i += 256) s += (row[i] != 0);
  } else {
    const int* row = (const int*)mraw + (size_t)b * Tsz;
    for (int i = tid; i < Tsz; i += 256) s += (row[i] != 0);
  }
  red[tid] = s; __syncthreads();
  for (int off = 128; off; off >>= 1) {
    if (tid < off) red[tid] += red[tid + off];
    __syncthreads();
  }
  if (tid == 0) lens[b] = red[0];
}

// ---------------- Whh transpose: WhhT[j][r] = Whh[r][j] ----------------
__global__ __launch_bounds__(256) void k_transpose(const float* __restrict__ Whh,
                                                   float* __restrict__ WhhT) {
  int idx = blockIdx.x * 256 + threadIdx.x;
  if (idx >= Gsz * Hsz) return;
  int r = idx / Hsz, j = idx - r * Hsz;
  WhhT[(size_t)j * Gsz + r] = Whh[idx];
}

// ---------------- input projection GEMM with fused embedding gather ----
// Chunked over time: rows n in [0, Bsz*TC), b = n>>tcShift, t = t0 + (n & TC-1)
// P[n, j] = sum_k embed[x[b,t], k] * W[j, k] + bias[j]
#define BM 64
#define BN 160
#define BK 20
__global__ __launch_bounds__(256) void k_gemm(const int* __restrict__ x,
                                              const float* __restrict__ embed,
                                              const float* __restrict__ W,
                                              const float* __restrict__ bias,
                                              float* __restrict__ P,
                                              int t0, int tcShift) {
  __shared__ __align__(16) float As[BK][BM];
  __shared__ __align__(16) float Bs[BK][BN];
  __shared__ int toks[BM];
  int tid = threadIdx.x;
  int n0 = blockIdx.x * BM;
  int j0 = blockIdx.y * BN;
  if (tid < BM) {
    int n = n0 + tid;
    int bb = n >> tcShift;
    int tl = n & ((1 << tcShift) - 1);
    toks[tid] = x[(bb << 10) + t0 + tl];
  }
  float acc[8][5];
#pragma unroll
  for (int i = 0; i < 8; i++)
#pragma unroll
    for (int j = 0; j < 5; j++) acc[i][j] = 0.f;
  int rg = tid >> 5;
  int cg = tid & 31;
  for (int k0 = 0; k0 < Esz; k0 += BK) {
    __syncthreads();
    for (int idx = tid; idx < BM * 5; idx += 256) {
      int r = idx / 5, q = idx % 5;
      const float4 v = *reinterpret_cast<const float4*>(
          embed + (size_t)toks[r] * Esz + k0 + q * 4);
      As[q * 4 + 0][r] = v.x; As[q * 4 + 1][r] = v.y;
      As[q * 4 + 2][r] = v.z; As[q * 4 + 3][r] = v.w;
    }
    for (int idx = tid; idx < BN * 5; idx += 256) {
      int j = idx / 5, q = idx % 5;
      const float4 v = *reinterpret_cast<const float4*>(
          W + (size_t)(j0 + j) * Esz + k0 + q * 4);
      Bs[q * 4 + 0][j] = v.x; Bs[q * 4 + 1][j] = v.y;
      Bs[q * 4 + 2][j] = v.z; Bs[q * 4 + 3][j] = v.w;
    }
    __syncthreads();
#pragma unroll
    for (int kk = 0; kk < BK; ++kk) {
      float4 a0 = *reinterpret_cast<const float4*>(&As[kk][rg * 8]);
      float4 a1 = *reinterpret_cast<const float4*>(&As[kk][rg * 8 + 4]);
      float a[8] = {a0.x, a0.y, a0.z, a0.w, a1.x, a1.y, a1.z, a1.w};
      float bv[5];
#pragma unroll
      for (int j = 0; j < 5; j++) bv[j] = Bs[kk][cg + 32 * j];
#pragma unroll
      for (int i = 0; i < 8; i++)
#pragma unroll
        for (int j = 0; j < 5; j++) acc[i][j] = fmaf(a[i], bv[j], acc[i][j]);
    }
  }
#pragma unroll
  for (int j = 0; j < 5; j++) {
    int col = j0 + cg + 32 * j;
    float bb = bias[col];
#pragma unroll
    for (int i = 0; i < 8; i++) {
      int n = n0 + rg * 8 + i;
      P[(size_t)n * Gsz + col] = acc[i][j] + bb;
    }
  }
}

// ---------------- masked LSTM recurrence (one WG of 512 per batch elem) ---
// Processes t in [t0, t0+TC) intersect [0, len). h,c persist in hc[] between
// chunk launches. Fused Kuma-head partial dots: za/zb[n] = h_t . Wa/Wb slice.
__global__ __launch_bounds__(512) void k_lstm(const float* __restrict__ P,
                                              const float* __restrict__ WhhT,
                                              const int* __restrict__ lens,
                                              const float* __restrict__ Wa,
                                              const float* __restrict__ Wb,
                                              float* __restrict__ hc,
                                              float* __restrict__ za,
                                              float* __restrict__ zb,
                                              int t0, int TC, int reverse,
                                              int init) {
  __shared__ __align__(16) float h[Hsz];
  __shared__ __align__(16) float c[Hsz];
  __shared__ __align__(16) float g[Gsz];
  __shared__ float redA[8], redB[8];
  int b = blockIdx.x, tid = threadIdx.x;
  int len = lens[b];
  float* hcb = hc + (size_t)b * 2 * Hsz;
  float wa = 0.f, wb = 0.f;
  if (tid < Hsz) {
    h[tid] = init ? 0.f : hcb[tid];
    c[tid] = init ? 0.f : hcb[Hsz + tid];
    int off = reverse ? Hsz : 0;
    wa = Wa[off + tid]; wb = Wb[off + tid];
  }
  __syncthreads();
  int lo = t0;
  int hi = t0 + TC; if (len < hi) hi = len;
  int nsteps = hi - lo; if (nsteps < 0) nsteps = 0;
  for (int s = 0; s < nsteps; ++s) {
    int t = reverse ? (hi - 1 - s) : (lo + s);
    const float* __restrict__ Prow = P + ((size_t)b * TC + (t - t0)) * Gsz;
    if (tid < 400) {
      float2 acc = *reinterpret_cast<const float2*>(Prow + 2 * tid);
      const float* wp = WhhT + 2 * tid;
#pragma unroll 8
      for (int j = 0; j < Hsz; ++j) {
        float hj = h[j];
        float2 w = *reinterpret_cast<const float2*>(wp + (size_t)j * Gsz);
        acc.x = fmaf(w.x, hj, acc.x);
        acc.y = fmaf(w.y, hj, acc.y);
      }
      *reinterpret_cast<float2*>(g + 2 * tid) = acc;
    }
    __syncthreads();   // g ready; h reads complete
    float pa = 0.f, pb = 0.f;
    if (tid < Hsz) {
      float gi = g[tid], gf = g[Hsz + tid];
      float gc = g[2 * Hsz + tid], go = g[3 * Hsz + tid];
      float ig = 1.f / (1.f + expf(-gi));
      float fg = 1.f / (1.f + expf(-gf));
      float gt = tanhf(gc);
      float og = 1.f / (1.f + expf(-go));
      float cn = fmaf(fg, c[tid], ig * gt);
      float hn = og * tanhf(cn);
      c[tid] = cn; h[tid] = hn;
      pa = hn * wa; pb = hn * wb;
    }
#pragma unroll
    for (int off = 32; off; off >>= 1) {
      pa += __shfl_down(pa, off);
      pb += __shfl_down(pb, off);
    }
    if ((tid & 63) == 0) { redA[tid >> 6] = pa; redB[tid >> 6] = pb; }
    __syncthreads();   // redA/B ready; h writes visible for next gate pass
    if (tid == 0) {
      float sa = 0.f, sb = 0.f;
#pragma unroll
      for (int w = 0; w < 8; ++w) { sa += redA[w]; sb += redB[w]; }
      za[(size_t)b * Tsz + t] = sa;
      zb[(size_t)b * Tsz + t] = sb;
    }
  }
  __syncthreads();
  if (tid < Hsz) { hcb[tid] = h[tid]; hcb[Hsz + tid] = c[tid]; }
}

// ---------------- Kuma head per token (double precision) ---------------
__global__ __launch_bounds__(256) void k_head(const float* __restrict__ zaf,
                                              const float* __restrict__ zbf,
                                              const float* __restrict__ zab,
                                              const float* __restrict__ zbb,
                                              const int* __restrict__ lens,
                                              const float* __restrict__ ba,
                                              const float* __restrict__ bb,
                                              float* __restrict__ zp) {
  int n = blockIdx.x * 256 + threadIdx.x;
  if (n >= NTOK) return;
  int b = n >> 10, t = n & 1023;
  if (t >= lens[b]) { zp[n] = 0.f; return; }
  double av = ((double)zaf[n] + (double)zab[n]) * 100.0 + (double)ba[0];
  double bv = ((double)zbf[n] + (double)zbb[n]) * 100.0 + (double)bb[0];
  double a  = av > 0.0 ? av + log1p(exp(-av)) : log1p(exp(av));
  double bk = bv > 0.0 ? bv + log1p(exp(-bv)) : log1p(exp(bv));
  a  = fmin(fmax(a, 1e-6), 100.0);
  bk = fmin(fmax(bk, 1e-6), 100.0);
  double ia = 1.0 + 1.0 / a;
  double lb = lgamma(ia) + lgamma(bk) - lgamma(ia + bk);
  double mean = bk * exp(lb);
  mean = -0.1 + 1.2 * mean;
  mean = fmin(fmax(mean, 0.0), 1.0);
  zp[n] = (float)mean;
}

// ---------------- stable top-k selection per row -----------------------
__global__ __launch_bounds__(256) void k_select(const float* __restrict__ zp,
                                                const int* __restrict__ lens,
                                                float* __restrict__ out) {
  __shared__ float zv[Tsz];
  __shared__ float wbv[4];
  __shared__ int wbi[4];
  __shared__ int stop;
  int b = blockIdx.x, tid = threadIdx.x;
  const float* row = zp + (size_t)b * Tsz;
  for (int i = tid; i < Tsz; i += 256) zv[i] = row[i];
  if (tid == 0) stop = 0;
  int len = lens[b];
  int k = (int)rintf(0.1f * (float)len);  // jnp round-half-even on f32 product
  __syncthreads();
  for (int it = 0; it < k; ++it) {
    float bvl = -1.f; int bil = 0;
#pragma unroll
    for (int s = 0; s < 4; s++) {
      int i = tid * 4 + s;
      float v = zv[i];
      if (v > bvl) { bvl = v; bil = i; }
    }
    for (int off = 32; off; off >>= 1) {
      float ov = __shfl_down(bvl, off);
      int   oi = __shfl_down(bil, off);
      if (ov > bvl || (ov == bvl && oi < bil)) { bvl = ov; bil = oi; }
    }
    int w = tid >> 6;
    if ((tid & 63) == 0) { wbv[w] = bvl; wbi[w] = bil; }
    __syncthreads();
    if (tid == 0) {
      float fb = wbv[0]; int fi = wbi[0];
      for (int q = 1; q < 4; q++)
        if (wbv[q] > fb || (wbv[q] == fb && wbi[q] < fi)) { fb = wbv[q]; fi = wbi[q]; }
      if (fb <= 0.f) stop = 1;               // z_probs > 0 required
      else { out[(size_t)b * Tsz + fi] = 1.0f; zv[fi] = -1e30f; }
    }
    __syncthreads();
    if (stop) break;
  }
}

extern "C" void kernel_launch(void* const* d_in, const int* in_sizes, int n_in,
                              void* d_out, int out_size, void* d_ws, size_t ws_size,
                              hipStream_t stream) {
  const int*   x      = (const int*)d_in[0];
  const void*  mask   = d_in[1];
  const float* embed  = (const float*)d_in[2];
  const float* Wih_f  = (const float*)d_in[3];
  const float* Whh_f  = (const float*)d_in[4];
  const float* b_f    = (const float*)d_in[5];
  const float* Wih_b  = (const float*)d_in[6];
  const float* Whh_b  = (const float*)d_in[7];
  const float* b_b    = (const float*)d_in[8];
  const float* Wa     = (const float*)d_in[9];
  const float* ba     = (const float*)d_in[10];
  const float* Wb     = (const float*)d_in[11];
  const float* bb     = (const float*)d_in[12];
  float* out = (float*)d_out;

  // ---- adaptive time-chunk so workspace always fits ----
  size_t fixedBytes = (5 * (size_t)NTOK + (size_t)Bsz * 2 * Hsz +
                       (size_t)Hsz * Gsz + 256) * sizeof(float) +
                      Bsz * sizeof(int) + 256;
  int TC = 64;
  const int cand[5] = {1024, 512, 256, 128, 64};
  for (int i = 0; i < 5; i++) {
    size_t need = fixedBytes + (size_t)Bsz * cand[i] * Gsz * sizeof(float);
    if (need <= ws_size) { TC = cand[i]; break; }
  }
  int tcShift = 31 - __builtin_clz((unsigned)TC);

  float* P    = (float*)d_ws;                       // Bsz*TC*Gsz
  float* zaf  = P + (size_t)Bsz * TC * Gsz;         // NTOK
  float* zbf  = zaf + NTOK;
  float* zab  = zbf + NTOK;
  float* zbb  = zab + NTOK;
  float* zp   = zbb + NTOK;
  float* hc   = zp + NTOK;                          // Bsz*2*Hsz
  float* WhhT = hc + (size_t)Bsz * 2 * Hsz;         // Hsz*Gsz (+pad)
  int*   lens = (int*)(WhhT + (size_t)Hsz * Gsz + 256);

  k_lengths<<<Bsz, 256, 0, stream>>>(mask, lens);

  int nch = Tsz / TC;
  dim3 gg((Bsz * TC) / BM, Gsz / BN);
  const int tgrid = (Gsz * Hsz + 255) / 256;

  // forward direction
  k_transpose<<<tgrid, 256, 0, stream>>>(Whh_f, WhhT);
  for (int ci = 0; ci < nch; ++ci) {
    int t0 = ci * TC;
    k_gemm<<<gg, 256, 0, stream>>>(x, embed, Wih_f, b_f, P, t0, tcShift);
    k_lstm<<<Bsz, 512, 0, stream>>>(P, WhhT, lens, Wa, Wb, hc, zaf, zbf,
                                    t0, TC, 0, ci == 0);
  }
  // backward direction (chunks from high t to low t)
  k_transpose<<<tgrid, 256, 0, stream>>>(Whh_b, WhhT);
  for (int ci = nch - 1; ci >= 0; --ci) {
    int t0 = ci * TC;
    k_gemm<<<gg, 256, 0, stream>>>(x, embed, Wih_b, b_b, P, t0, tcShift);
    k_lstm<<<Bsz, 512, 0, stream>>>(P, WhhT, lens, Wa, Wb, hc, zab, zbb,
                                    t0, TC, 1, ci == nch - 1);
  }

  k_head<<<NTOK / 256, 256, 0, stream>>>(zaf, zbf, zab, zbb, lens, ba, bb, zp);

  hipMemsetAsync(d_out, 0, (size_t)out_size * sizeof(float), stream);
  k_select<<<Bsz, 256, 0, stream>>>(zp, lens, out);
}

// Round 3
// 11858.154 us; speedup vs baseline: 1.8673x; 1.8673x over previous
//
#include <hip/hip_runtime.h>
#include <math.h>

#define Bsz 64
#define Tsz 1024
#define Esz 300
#define Hsz 200
#define Gsz 800   // 4*H
#define NTOK (Bsz*Tsz)

// ---------------- lengths: lens[b] = sum(mask[b,:]) ----------------
// mask may be 1-byte bool or 4-byte int. len >= 512 always, so byte[1]
// is 1 iff 1-byte layout.
__global__ __launch_bounds__(256) void k_lengths(const void* __restrict__ mraw,
                                                 int* __restrict__ lens) {
  __shared__ int red[256];
  const unsigned char* mb = (const unsigned char*)mraw;
  const int isbool = (mb[1] != 0);
  int b = blockIdx.x, tid = threadIdx.x;
  int s = 0;
  if (isbool) {
    const unsigned char* row = mb + (size_t)b * Tsz;
    for (int i = tid; i < Tsz; i += 256) s += (row[i] != 0);
  } else {
    const int* row = (const int*)mraw + (size_t)b * Tsz;
    for (int i = tid; i < Tsz; i += 256) s += (row[i] != 0);
  }
  red[tid] = s; __syncthreads();
  for (int off = 128; off; off >>= 1) {
    if (tid < off) red[tid] += red[tid + off];
    __syncthreads();
  }
  if (tid == 0) lens[b] = red[0];
}

// ---------------- Whh transpose: WhhT[j][r] = Whh[r][j] ----------------
__global__ __launch_bounds__(256) void k_transpose(const float* __restrict__ Whh,
                                                   float* __restrict__ WhhT) {
  int idx = blockIdx.x * 256 + threadIdx.x;
  if (idx >= Gsz * Hsz) return;
  int r = idx / Hsz, j = idx - r * Hsz;
  WhhT[(size_t)j * Gsz + r] = Whh[idx];
}

// ---------------- input projection GEMM with fused embedding gather ----
#define BM 64
#define BN 160
#define BK 20
__global__ __launch_bounds__(256) void k_gemm(const int* __restrict__ x,
                                              const float* __restrict__ embed,
                                              const float* __restrict__ W,
                                              const float* __restrict__ bias,
                                              float* __restrict__ P,
                                              int t0, int tcShift) {
  __shared__ __align__(16) float As[BK][BM];
  __shared__ __align__(16) float Bs[BK][BN];
  __shared__ int toks[BM];
  int tid = threadIdx.x;
  int n0 = blockIdx.x * BM;
  int j0 = blockIdx.y * BN;
  if (tid < BM) {
    int n = n0 + tid;
    int bb = n >> tcShift;
    int tl = n & ((1 << tcShift) - 1);
    toks[tid] = x[(bb << 10) + t0 + tl];
  }
  float acc[8][5];
#pragma unroll
  for (int i = 0; i < 8; i++)
#pragma unroll
    for (int j = 0; j < 5; j++) acc[i][j] = 0.f;
  int rg = tid >> 5;
  int cg = tid & 31;
  for (int k0 = 0; k0 < Esz; k0 += BK) {
    __syncthreads();
    for (int idx = tid; idx < BM * 5; idx += 256) {
      int r = idx / 5, q = idx % 5;
      const float4 v = *reinterpret_cast<const float4*>(
          embed + (size_t)toks[r] * Esz + k0 + q * 4);
      As[q * 4 + 0][r] = v.x; As[q * 4 + 1][r] = v.y;
      As[q * 4 + 2][r] = v.z; As[q * 4 + 3][r] = v.w;
    }
    for (int idx = tid; idx < BN * 5; idx += 256) {
      int j = idx / 5, q = idx % 5;
      const float4 v = *reinterpret_cast<const float4*>(
          W + (size_t)(j0 + j) * Esz + k0 + q * 4);
      Bs[q * 4 + 0][j] = v.x; Bs[q * 4 + 1][j] = v.y;
      Bs[q * 4 + 2][j] = v.z; Bs[q * 4 + 3][j] = v.w;
    }
    __syncthreads();
#pragma unroll
    for (int kk = 0; kk < BK; ++kk) {
      float4 a0 = *reinterpret_cast<const float4*>(&As[kk][rg * 8]);
      float4 a1 = *reinterpret_cast<const float4*>(&As[kk][rg * 8 + 4]);
      float a[8] = {a0.x, a0.y, a0.z, a0.w, a1.x, a1.y, a1.z, a1.w};
      float bv[5];
#pragma unroll
      for (int j = 0; j < 5; j++) bv[j] = Bs[kk][cg + 32 * j];
#pragma unroll
      for (int i = 0; i < 8; i++)
#pragma unroll
        for (int j = 0; j < 5; j++) acc[i][j] = fmaf(a[i], bv[j], acc[i][j]);
    }
  }
#pragma unroll
  for (int j = 0; j < 5; j++) {
    int col = j0 + cg + 32 * j;
    float bb = bias[col];
#pragma unroll
    for (int i = 0; i < 8; i++) {
      int n = n0 + rg * 8 + i;
      P[(size_t)n * Gsz + col] = acc[i][j] + bb;
    }
  }
}

// ---------------- masked LSTM, both directions concurrently ------------
// 128 WGs: bid<64 forward batch bid, bid>=64 backward batch bid-64.
// 512 threads; threads 0..399 each own a float2 column pair of WhhT;
// 8-deep ring-buffer prefetch keeps ~8 global loads in flight.
#define PF 8
__global__ __launch_bounds__(512, 2) void k_lstm(
    const float* __restrict__ Pf, const float* __restrict__ Pb,
    const float* __restrict__ WhhTf, const float* __restrict__ WhhTb,
    const int* __restrict__ lens,
    const float* __restrict__ Wa, const float* __restrict__ Wb,
    float* __restrict__ hcF, float* __restrict__ hcB,
    float* __restrict__ zaf, float* __restrict__ zbf,
    float* __restrict__ zab, float* __restrict__ zbb,
    int t0f, int t0b, int TC, int init) {
  __shared__ __align__(16) float h[Hsz];
  __shared__ __align__(16) float c[Hsz];
  __shared__ __align__(16) float g[Gsz];
  __shared__ float redA[8], redB[8];
  int bid = blockIdx.x, tid = threadIdx.x;
  int rev = bid >> 6;              // 0 fwd, 1 bwd
  int b = bid & 63;
  int len = lens[b];
  const float* P    = rev ? Pb : Pf;
  const float* WhhT = rev ? WhhTb : WhhTf;
  float* hcb = (rev ? hcB : hcF) + (size_t)b * 2 * Hsz;
  float* za  = rev ? zab : zaf;
  float* zb  = rev ? zbb : zbf;
  int t0 = rev ? t0b : t0f;
  float wa = 0.f, wb = 0.f;
  if (tid < Hsz) {
    h[tid] = init ? 0.f : hcb[tid];
    c[tid] = init ? 0.f : hcb[Hsz + tid];
    int off = rev ? Hsz : 0;
    wa = Wa[off + tid]; wb = Wb[off + tid];
  }
  __syncthreads();
  int lo = t0;
  int hi = t0 + TC; if (len < hi) hi = len;
  int nsteps = hi - lo; if (nsteps < 0) nsteps = 0;
  const float2* __restrict__ wp =
      reinterpret_cast<const float2*>(WhhT) + tid;   // stride 400 per j
  for (int s = 0; s < nsteps; ++s) {
    int t = rev ? (hi - 1 - s) : (lo + s);
    const float* __restrict__ Prow = P + ((size_t)b * TC + (t - t0)) * Gsz;
    if (tid < 400) {
      float2 acc = *reinterpret_cast<const float2*>(Prow + 2 * tid);
      float2 wbuf[PF];
#pragma unroll
      for (int i = 0; i < PF; i++) wbuf[i] = wp[i * 400];
#pragma unroll 8
      for (int j = 0; j < 200 - PF; ++j) {
        float2 w = wbuf[j & (PF - 1)];
        wbuf[j & (PF - 1)] = wp[(j + PF) * 400];
        float hj = h[j];
        acc.x = fmaf(w.x, hj, acc.x);
        acc.y = fmaf(w.y, hj, acc.y);
      }
#pragma unroll
      for (int j = 200 - PF; j < 200; ++j) {
        float2 w = wbuf[j & (PF - 1)];
        float hj = h[j];
        acc.x = fmaf(w.x, hj, acc.x);
        acc.y = fmaf(w.y, hj, acc.y);
      }
      *reinterpret_cast<float2*>(g + 2 * tid) = acc;
    }
    __syncthreads();   // g ready; all h reads complete
    float pa = 0.f, pb = 0.f;
    if (tid < Hsz) {
      float gi = g[tid], gf = g[Hsz + tid];
      float gc = g[2 * Hsz + tid], go = g[3 * Hsz + tid];
      float ig = 1.f / (1.f + expf(-gi));
      float fg = 1.f / (1.f + expf(-gf));
      float gt = tanhf(gc);
      float og = 1.f / (1.f + expf(-go));
      float cn = fmaf(fg, c[tid], ig * gt);
      float hn = og * tanhf(cn);
      c[tid] = cn; h[tid] = hn;
      pa = hn * wa; pb = hn * wb;
    }
#pragma unroll
    for (int off = 32; off; off >>= 1) {
      pa += __shfl_down(pa, off);
      pb += __shfl_down(pb, off);
    }
    if ((tid & 63) == 0) { redA[tid >> 6] = pa; redB[tid >> 6] = pb; }
    __syncthreads();   // redA/B ready; h writes visible for next step
    if (tid == 0) {
      float sa = 0.f, sb = 0.f;
#pragma unroll
      for (int w = 0; w < 8; ++w) { sa += redA[w]; sb += redB[w]; }
      za[(size_t)b * Tsz + t] = sa;
      zb[(size_t)b * Tsz + t] = sb;
    }
  }
  __syncthreads();
  if (tid < Hsz) { hcb[tid] = h[tid]; hcb[Hsz + tid] = c[tid]; }
}

// ---------------- Kuma head per token (double precision) ---------------
__global__ __launch_bounds__(256) void k_head(const float* __restrict__ zaf,
                                              const float* __restrict__ zbf,
                                              const float* __restrict__ zab,
                                              const float* __restrict__ zbb,
                                              const int* __restrict__ lens,
                                              const float* __restrict__ ba,
                                              const float* __restrict__ bb,
                                              float* __restrict__ zp) {
  int n = blockIdx.x * 256 + threadIdx.x;
  if (n >= NTOK) return;
  int b = n >> 10, t = n & 1023;
  if (t >= lens[b]) { zp[n] = 0.f; return; }
  double av = ((double)zaf[n] + (double)zab[n]) * 100.0 + (double)ba[0];
  double bv = ((double)zbf[n] + (double)zbb[n]) * 100.0 + (double)bb[0];
  double a  = av > 0.0 ? av + log1p(exp(-av)) : log1p(exp(av));
  double bk = bv > 0.0 ? bv + log1p(exp(-bv)) : log1p(exp(bv));
  a  = fmin(fmax(a, 1e-6), 100.0);
  bk = fmin(fmax(bk, 1e-6), 100.0);
  double ia = 1.0 + 1.0 / a;
  double lb = lgamma(ia) + lgamma(bk) - lgamma(ia + bk);
  double mean = bk * exp(lb);
  mean = -0.1 + 1.2 * mean;
  mean = fmin(fmax(mean, 0.0), 1.0);
  zp[n] = (float)mean;
}

// ---------------- stable top-k selection per row -----------------------
__global__ __launch_bounds__(256) void k_select(const float* __restrict__ zp,
                                                const int* __restrict__ lens,
                                                float* __restrict__ out) {
  __shared__ float zv[Tsz];
  __shared__ float wbv[4];
  __shared__ int wbi[4];
  __shared__ int stop;
  int b = blockIdx.x, tid = threadIdx.x;
  const float* row = zp + (size_t)b * Tsz;
  for (int i = tid; i < Tsz; i += 256) zv[i] = row[i];
  if (tid == 0) stop = 0;
  int len = lens[b];
  int k = (int)rintf(0.1f * (float)len);
  __syncthreads();
  for (int it = 0; it < k; ++it) {
    float bvl = -1.f; int bil = 0;
#pragma unroll
    for (int s = 0; s < 4; s++) {
      int i = tid * 4 + s;
      float v = zv[i];
      if (v > bvl) { bvl = v; bil = i; }
    }
    for (int off = 32; off; off >>= 1) {
      float ov = __shfl_down(bvl, off);
      int   oi = __shfl_down(bil, off);
      if (ov > bvl || (ov == bvl && oi < bil)) { bvl = ov; bil = oi; }
    }
    int w = tid >> 6;
    if ((tid & 63) == 0) { wbv[w] = bvl; wbi[w] = bil; }
    __syncthreads();
    if (tid == 0) {
      float fb = wbv[0]; int fi = wbi[0];
      for (int q = 1; q < 4; q++)
        if (wbv[q] > fb || (wbv[q] == fb && wbi[q] < fi)) { fb = wbv[q]; fi = wbi[q]; }
      if (fb <= 0.f) stop = 1;
      else { out[(size_t)b * Tsz + fi] = 1.0f; zv[fi] = -1e30f; }
    }
    __syncthreads();
    if (stop) break;
  }
}

extern "C" void kernel_launch(void* const* d_in, const int* in_sizes, int n_in,
                              void* d_out, int out_size, void* d_ws, size_t ws_size,
                              hipStream_t stream) {
  const int*   x      = (const int*)d_in[0];
  const void*  mask   = d_in[1];
  const float* embed  = (const float*)d_in[2];
  const float* Wih_f  = (const float*)d_in[3];
  const float* Whh_f  = (const float*)d_in[4];
  const float* b_f    = (const float*)d_in[5];
  const float* Wih_b  = (const float*)d_in[6];
  const float* Whh_b  = (const float*)d_in[7];
  const float* b_b    = (const float*)d_in[8];
  const float* Wa     = (const float*)d_in[9];
  const float* ba     = (const float*)d_in[10];
  const float* Wb     = (const float*)d_in[11];
  const float* bb     = (const float*)d_in[12];
  float* out = (float*)d_out;

  // ---- adaptive time-chunk: need TWO P buffers (fwd + bwd) ----
  size_t fixedBytes = (5 * (size_t)NTOK + 2 * (size_t)Bsz * 2 * Hsz +
                       2 * ((size_t)Hsz * Gsz + 256)) * sizeof(float) +
                      Bsz * sizeof(int) + 1024;
  int TC = 16;
  const int cand[6] = {512, 256, 128, 64, 32, 16};
  for (int i = 0; i < 6; i++) {
    size_t need = fixedBytes + 2 * (size_t)Bsz * cand[i] * Gsz * sizeof(float);
    if (need <= ws_size) { TC = cand[i]; break; }
  }
  int tcShift = 31 - __builtin_clz((unsigned)TC);

  float* Pf    = (float*)d_ws;                      // Bsz*TC*Gsz
  float* Pb    = Pf + (size_t)Bsz * TC * Gsz;       // Bsz*TC*Gsz
  float* zaf   = Pb + (size_t)Bsz * TC * Gsz;       // NTOK
  float* zbf   = zaf + NTOK;
  float* zab   = zbf + NTOK;
  float* zbb   = zab + NTOK;
  float* zp    = zbb + NTOK;
  float* hcF   = zp + NTOK;                         // Bsz*2*Hsz
  float* hcB   = hcF + (size_t)Bsz * 2 * Hsz;
  float* WhhTf = hcB + (size_t)Bsz * 2 * Hsz;       // Hsz*Gsz + pad
  float* WhhTb = WhhTf + (size_t)Hsz * Gsz + 256;
  int*   lens  = (int*)(WhhTb + (size_t)Hsz * Gsz + 256);

  k_lengths<<<Bsz, 256, 0, stream>>>(mask, lens);

  const int tgrid = (Gsz * Hsz + 255) / 256;
  k_transpose<<<tgrid, 256, 0, stream>>>(Whh_f, WhhTf);
  k_transpose<<<tgrid, 256, 0, stream>>>(Whh_b, WhhTb);

  int nch = Tsz / TC;
  dim3 gg((Bsz * TC) / BM, Gsz / BN);
  for (int ci = 0; ci < nch; ++ci) {
    int t0f = ci * TC;
    int t0b = (nch - 1 - ci) * TC;
    k_gemm<<<gg, 256, 0, stream>>>(x, embed, Wih_f, b_f, Pf, t0f, tcShift);
    k_gemm<<<gg, 256, 0, stream>>>(x, embed, Wih_b, b_b, Pb, t0b, tcShift);
    k_lstm<<<2 * Bsz, 512, 0, stream>>>(Pf, Pb, WhhTf, WhhTb, lens, Wa, Wb,
                                        hcF, hcB, zaf, zbf, zab, zbb,
                                        t0f, t0b, TC, ci == 0);
  }

  k_head<<<NTOK / 256, 256, 0, stream>>>(zaf, zbf, zab, zbb, lens, ba, bb, zp);

  hipMemsetAsync(d_out, 0, (size_t)out_size * sizeof(float), stream);
  k_select<<<Bsz, 256, 0, stream>>>(zp, lens, out);
}